// Round 1
// baseline (638.206 us; speedup 1.0000x reference)
//
#include <hip/hip_runtime.h>

// Problem constants (derived at launch from sizes, these are just for reference):
// N_NODES=100000, N_FEAT=128, N_EDGES=640000, BATCH=50000
// out[B, 256] f32: cols 0..127 = x[:B], cols 128..255 = segment-sum of x[src] for dst<B

#define NFEAT 128
#define NF4   32   // 128 floats = 32 float4 per row

// Kernel 1: out[row, 0:128] = x[row]; out[row, 128:256] = 0
// One thread per float4 of the output (64 float4 per output row).
__global__ void init_out_kernel(const float4* __restrict__ x4,
                                float4* __restrict__ out4,
                                int B) {
    int t = blockIdx.x * blockDim.x + threadIdx.x;
    int total = B * 64;
    if (t >= total) return;
    int row = t >> 6;       // output row
    int c   = t & 63;       // float4 column within row
    float4 v;
    if (c < NF4) {
        v = x4[(size_t)row * NF4 + c];
    } else {
        v = make_float4(0.f, 0.f, 0.f, 0.f);
    }
    out4[t] = v;
}

// Kernel 2: 32 threads per edge; lane c handles float4 chunk c of the feature row.
// Consecutive threads within a 32-lane group gather consecutive float4s of
// x[src] (512 B contiguous -> coalesced), then atomically add into out[dst, 128+].
__global__ void edge_scatter_kernel(const float* __restrict__ x,
                                    const int* __restrict__ src,
                                    const int* __restrict__ dst,
                                    float* __restrict__ out,
                                    int E, int B) {
    int t = blockIdx.x * blockDim.x + threadIdx.x;
    int e = t >> 5;          // edge index (32 threads per edge)
    if (e >= E) return;
    int d = dst[e];
    if (d >= B) return;      // edge outside target batch
    int c = t & 31;          // float4 chunk within the feature row
    int s = src[e];
    const float4 v = ((const float4*)(x + (size_t)s * NFEAT))[c];
    float* o = out + (size_t)d * 256 + NFEAT + c * 4;
    unsafeAtomicAdd(o + 0, v.x);
    unsafeAtomicAdd(o + 1, v.y);
    unsafeAtomicAdd(o + 2, v.z);
    unsafeAtomicAdd(o + 3, v.w);
}

extern "C" void kernel_launch(void* const* d_in, const int* in_sizes, int n_in,
                              void* d_out, int out_size, void* d_ws, size_t ws_size,
                              hipStream_t stream) {
    const float* x  = (const float*)d_in[0];
    const int*   ei = (const int*)d_in[1];
    // d_in[2] is batch_size (device scalar) — derive B from out_size instead.
    const int E = in_sizes[1] / 2;
    const int B = out_size / 256;   // 2*NFEAT cols per output row
    float* out = (float*)d_out;

    // 1) init: copy left half, zero right half (d_out is poisoned 0xAA each call)
    {
        int total = B * 64;
        int blocks = (total + 255) / 256;
        init_out_kernel<<<blocks, 256, 0, stream>>>((const float4*)x, (float4*)out, B);
    }
    // 2) scatter-sum valid edges
    {
        long long total = (long long)E * 32;
        int blocks = (int)((total + 255) / 256);
        edge_scatter_kernel<<<blocks, 256, 0, stream>>>(x, ei, ei + E, out, E, B);
    }
}

// Round 2
// 184.821 us; speedup vs baseline: 3.4531x; 3.4531x over previous
//
#include <hip/hip_runtime.h>

#define NFEAT 128

// ---------------- CSR-bucketed path (no float atomics) ----------------
// ws layout (ints): cnt[B] | off[B] | deg[B] | cursor[1] | bucket[E]

__global__ void zero_ws_kernel(int* __restrict__ p, int n) {
    int t = blockIdx.x * blockDim.x + threadIdx.x;
    if (t < n) p[t] = 0;
}

__global__ void hist_kernel(const int* __restrict__ dst, int* __restrict__ cnt,
                            int E, int B) {
    int e = blockIdx.x * blockDim.x + threadIdx.x;
    if (e >= E) return;
    int d = dst[e];
    if (d < B) atomicAdd(&cnt[d], 1);
}

// Wave-aggregated segment-base allocation: one inclusive shuffle-scan per wave,
// a single global atomic per wave (781 total instead of 50k).
// Segments need to be contiguous, not ordered, so allocation order is free.
__global__ void alloc_kernel(const int* __restrict__ cnt, int* __restrict__ off,
                             int* __restrict__ deg, int* __restrict__ cursor, int B) {
    int t = blockIdx.x * blockDim.x + threadIdx.x;
    int lane = threadIdx.x & 63;
    int c = (t < B) ? cnt[t] : 0;
    int v = c;
    #pragma unroll
    for (int d = 1; d < 64; d <<= 1) {
        int n = __shfl_up(v, d, 64);
        if (lane >= d) v += n;
    }
    int total = __shfl(v, 63, 64);
    int base = 0;
    if (lane == 63 && total > 0) base = atomicAdd(cursor, total);
    base = __shfl(base, 63, 64);
    if (t < B) { off[t] = base + v - c; deg[t] = c; }
}

__global__ void scatter_kernel(const int* __restrict__ src, const int* __restrict__ dst,
                               int* __restrict__ cnt, const int* __restrict__ off,
                               int* __restrict__ bucket, int E, int B) {
    int e = blockIdx.x * blockDim.x + threadIdx.x;
    if (e >= E) return;
    int d = dst[e];
    if (d >= B) return;
    int old = atomicSub(&cnt[d], 1);        // positions off[d]..off[d]+count-1, each once
    bucket[off[d] + old - 1] = src[e];
}

// One wave per destination row: lane owns 2 feature columns (float2).
// Gathers x[src] rows (64 lanes x 8 B = 512 B coalesced per row), accumulates
// in registers, writes the whole 256-col output row once (left = x[d] copy).
__global__ void aggregate_kernel(const float2* __restrict__ x2,
                                 const int* __restrict__ off, const int* __restrict__ deg,
                                 const int* __restrict__ bucket,
                                 float2* __restrict__ out2, int B) {
    int w = (blockIdx.x * blockDim.x + threadIdx.x) >> 6;
    int lane = threadIdx.x & 63;
    if (w >= B) return;
    int base = off[w];
    int k = deg[w];
    float2 acc = make_float2(0.f, 0.f);
    for (int j = 0; j < k; ++j) {
        int s = bucket[base + j];           // wave-uniform -> broadcast load
        float2 v = x2[(size_t)s * 64 + lane];
        acc.x += v.x; acc.y += v.y;
    }
    float2 xd = x2[(size_t)w * 64 + lane];
    size_t o = (size_t)w * 128;
    out2[o + lane] = xd;                    // left half: copy x[w]
    out2[o + 64 + lane] = acc;              // right half: neighbor sum
}

// ---------------- Fallback path (R0: float atomics), used if ws too small ----
__global__ void init_out_kernel(const float4* __restrict__ x4,
                                float4* __restrict__ out4, int B) {
    int t = blockIdx.x * blockDim.x + threadIdx.x;
    if (t >= B * 64) return;
    int row = t >> 6, c = t & 63;
    float4 v = (c < 32) ? x4[(size_t)row * 32 + c] : make_float4(0.f, 0.f, 0.f, 0.f);
    out4[t] = v;
}

__global__ void edge_scatter_atomic_kernel(const float* __restrict__ x,
                                           const int* __restrict__ src,
                                           const int* __restrict__ dst,
                                           float* __restrict__ out, int E, int B) {
    int t = blockIdx.x * blockDim.x + threadIdx.x;
    int e = t >> 5;
    if (e >= E) return;
    int d = dst[e];
    if (d >= B) return;
    int c = t & 31;
    const float4 v = ((const float4*)(x + (size_t)src[e] * NFEAT))[c];
    float* o = out + (size_t)d * 256 + NFEAT + c * 4;
    unsafeAtomicAdd(o + 0, v.x);
    unsafeAtomicAdd(o + 1, v.y);
    unsafeAtomicAdd(o + 2, v.z);
    unsafeAtomicAdd(o + 3, v.w);
}

extern "C" void kernel_launch(void* const* d_in, const int* in_sizes, int n_in,
                              void* d_out, int out_size, void* d_ws, size_t ws_size,
                              hipStream_t stream) {
    const float* x  = (const float*)d_in[0];
    const int*   ei = (const int*)d_in[1];
    const int E = in_sizes[1] / 2;
    const int B = out_size / (2 * NFEAT);
    float* out = (float*)d_out;
    const int* src = ei;
    const int* dst = ei + E;

    size_t need = ((size_t)3 * B + 1 + E) * sizeof(int);
    if (ws_size >= need) {
        int* cnt    = (int*)d_ws;
        int* off    = cnt + B;
        int* deg    = off + B;
        int* cursor = deg + B;
        int* bucket = cursor + 1;

        int nz = 3 * B + 1;
        zero_ws_kernel<<<(nz + 255) / 256, 256, 0, stream>>>(cnt, nz);
        hist_kernel<<<(E + 255) / 256, 256, 0, stream>>>(dst, cnt, E, B);
        alloc_kernel<<<(B + 255) / 256, 256, 0, stream>>>(cnt, off, deg, cursor, B);
        scatter_kernel<<<(E + 255) / 256, 256, 0, stream>>>(src, dst, cnt, off, bucket, E, B);
        aggregate_kernel<<<(B + 3) / 4, 256, 0, stream>>>(
            (const float2*)x, off, deg, bucket, (float2*)out, B);
    } else {
        init_out_kernel<<<(B * 64 + 255) / 256, 256, 0, stream>>>(
            (const float4*)x, (float4*)out, B);
        long long total = (long long)E * 32;
        edge_scatter_atomic_kernel<<<(int)((total + 255) / 256), 256, 0, stream>>>(
            x, src, dst, out, E, B);
    }
}

// Round 3
// 141.176 us; speedup vs baseline: 4.5206x; 1.3091x over previous
//
#include <hip/hip_runtime.h>

#define NFEAT 128
#define CAP 32        // per-destination bucket capacity (max deg ~22 for Pois(6.4))
#define OVF_CAP 4096  // overflow edge list capacity (expected use: 0)

// ---------------- Direct-binning path ----------------
// ws layout (ints): cnt[B] | ovf_cnt[1] | ovf[2*OVF_CAP] | bucket[B*CAP]

__global__ void zero_kernel(int* __restrict__ p, int n) {
    int t = blockIdx.x * blockDim.x + threadIdx.x;
    if (t < n) p[t] = 0;
}

// One pass over edges: claim a slot in dst's bucket, store src id.
__global__ void bin_kernel(const int* __restrict__ src, const int* __restrict__ dst,
                           int* __restrict__ cnt, int* __restrict__ ovf_cnt,
                           int* __restrict__ ovf, int* __restrict__ bucket,
                           int E, int B) {
    int e = blockIdx.x * blockDim.x + threadIdx.x;
    if (e >= E) return;
    int d = dst[e];
    if (d >= B) return;
    int s = src[e];
    int pos = atomicAdd(&cnt[d], 1);
    if (pos < CAP) {
        bucket[d * CAP + pos] = s;
    } else {
        int o = atomicAdd(ovf_cnt, 1);
        if (o < OVF_CAP) { ovf[2 * o] = s; ovf[2 * o + 1] = d; }
    }
}

// One wave per destination row. Lane owns 2 feature cols (float2; 64x8B = 512B
// coalesced per row access). All neighbor ids preloaded into lanes with one
// coalesced read, broadcast via shfl; gather loop unrolled x4 so 4 independent
// row-gathers are in flight (breaks the R1 serial-latency chain).
__global__ void aggregate_kernel(const float2* __restrict__ x2,
                                 const int* __restrict__ cnt,
                                 const int* __restrict__ bucket,
                                 float2* __restrict__ out2, int B) {
    int w = (blockIdx.x * blockDim.x + threadIdx.x) >> 6;
    int lane = threadIdx.x & 63;
    if (w >= B) return;
    int k = cnt[w];
    if (k > CAP) k = CAP;
    int sid = (lane < k) ? bucket[w * CAP + lane] : 0;
    float2 xd = x2[(size_t)w * 64 + lane];   // independent: issue early
    float2 acc = make_float2(0.f, 0.f);
    int j = 0;
    for (; j + 4 <= k; j += 4) {
        int s0 = __shfl(sid, j,     64);
        int s1 = __shfl(sid, j + 1, 64);
        int s2 = __shfl(sid, j + 2, 64);
        int s3 = __shfl(sid, j + 3, 64);
        float2 v0 = x2[(size_t)s0 * 64 + lane];
        float2 v1 = x2[(size_t)s1 * 64 + lane];
        float2 v2 = x2[(size_t)s2 * 64 + lane];
        float2 v3 = x2[(size_t)s3 * 64 + lane];
        acc.x += (v0.x + v1.x) + (v2.x + v3.x);
        acc.y += (v0.y + v1.y) + (v2.y + v3.y);
    }
    for (; j < k; ++j) {
        int s = __shfl(sid, j, 64);
        float2 v = x2[(size_t)s * 64 + lane];
        acc.x += v.x; acc.y += v.y;
    }
    size_t o = (size_t)w * 128;
    out2[o + lane] = xd;          // left half: copy x[w]
    out2[o + 64 + lane] = acc;    // right half: neighbor sum
}

// Apply overflow edges (expected 0) with float atomics AFTER aggregate wrote out.
__global__ void ovf_apply_kernel(const float* __restrict__ x,
                                 const int* __restrict__ ovf_cnt,
                                 const int* __restrict__ ovf,
                                 float* __restrict__ out, int B) {
    int n = *ovf_cnt;
    if (n > OVF_CAP) n = OVF_CAP;
    int t = blockIdx.x * blockDim.x + threadIdx.x;
    int e = t >> 5;
    if (e >= n) return;
    int c = t & 31;
    int s = ovf[2 * e], d = ovf[2 * e + 1];
    const float4 v = ((const float4*)(x + (size_t)s * NFEAT))[c];
    float* o = out + (size_t)d * 256 + NFEAT + c * 4;
    unsafeAtomicAdd(o + 0, v.x);
    unsafeAtomicAdd(o + 1, v.y);
    unsafeAtomicAdd(o + 2, v.z);
    unsafeAtomicAdd(o + 3, v.w);
}

// ---------------- Fallback: R1 CSR path (passed) ----------------
__global__ void hist_kernel(const int* __restrict__ dst, int* __restrict__ cnt,
                            int E, int B) {
    int e = blockIdx.x * blockDim.x + threadIdx.x;
    if (e >= E) return;
    int d = dst[e];
    if (d < B) atomicAdd(&cnt[d], 1);
}

__global__ void alloc_kernel(const int* __restrict__ cnt, int* __restrict__ off,
                             int* __restrict__ deg, int* __restrict__ cursor, int B) {
    int t = blockIdx.x * blockDim.x + threadIdx.x;
    int lane = threadIdx.x & 63;
    int c = (t < B) ? cnt[t] : 0;
    int v = c;
    #pragma unroll
    for (int d = 1; d < 64; d <<= 1) {
        int n = __shfl_up(v, d, 64);
        if (lane >= d) v += n;
    }
    int total = __shfl(v, 63, 64);
    int base = 0;
    if (lane == 63 && total > 0) base = atomicAdd(cursor, total);
    base = __shfl(base, 63, 64);
    if (t < B) { off[t] = base + v - c; deg[t] = c; }
}

__global__ void scatter_kernel(const int* __restrict__ src, const int* __restrict__ dst,
                               int* __restrict__ cnt, const int* __restrict__ off,
                               int* __restrict__ bucket, int E, int B) {
    int e = blockIdx.x * blockDim.x + threadIdx.x;
    if (e >= E) return;
    int d = dst[e];
    if (d >= B) return;
    int old = atomicSub(&cnt[d], 1);
    bucket[off[d] + old - 1] = src[e];
}

__global__ void aggregate_csr_kernel(const float2* __restrict__ x2,
                                     const int* __restrict__ off, const int* __restrict__ deg,
                                     const int* __restrict__ bucket,
                                     float2* __restrict__ out2, int B) {
    int w = (blockIdx.x * blockDim.x + threadIdx.x) >> 6;
    int lane = threadIdx.x & 63;
    if (w >= B) return;
    int base = off[w];
    int k = deg[w];
    float2 acc = make_float2(0.f, 0.f);
    for (int j = 0; j < k; ++j) {
        int s = bucket[base + j];
        float2 v = x2[(size_t)s * 64 + lane];
        acc.x += v.x; acc.y += v.y;
    }
    float2 xd = x2[(size_t)w * 64 + lane];
    size_t o = (size_t)w * 128;
    out2[o + lane] = xd;
    out2[o + 64 + lane] = acc;
}

extern "C" void kernel_launch(void* const* d_in, const int* in_sizes, int n_in,
                              void* d_out, int out_size, void* d_ws, size_t ws_size,
                              hipStream_t stream) {
    const float* x  = (const float*)d_in[0];
    const int*   ei = (const int*)d_in[1];
    const int E = in_sizes[1] / 2;
    const int B = out_size / (2 * NFEAT);
    float* out = (float*)d_out;
    const int* src = ei;
    const int* dst = ei + E;

    size_t need_bin = ((size_t)B * (CAP + 1) + 1 + 2 * OVF_CAP) * sizeof(int);
    size_t need_csr = ((size_t)3 * B + 1 + E) * sizeof(int);

    if (ws_size >= need_bin) {
        int* cnt     = (int*)d_ws;
        int* ovf_cnt = cnt + B;
        int* ovf     = ovf_cnt + 1;
        int* bucket  = ovf + 2 * OVF_CAP;

        int nz = B + 1;
        zero_kernel<<<(nz + 255) / 256, 256, 0, stream>>>(cnt, nz);
        bin_kernel<<<(E + 255) / 256, 256, 0, stream>>>(src, dst, cnt, ovf_cnt, ovf, bucket, E, B);
        aggregate_kernel<<<(B + 3) / 4, 256, 0, stream>>>(
            (const float2*)x, cnt, bucket, (float2*)out, B);
        ovf_apply_kernel<<<(OVF_CAP * 32 + 255) / 256, 256, 0, stream>>>(x, ovf_cnt, ovf, out, B);
    } else {
        int* cnt    = (int*)d_ws;
        int* off    = cnt + B;
        int* deg    = off + B;
        int* cursor = deg + B;
        int* bucket = cursor + 1;
        int nz = 3 * B + 1;
        zero_kernel<<<(nz + 255) / 256, 256, 0, stream>>>(cnt, nz);
        hist_kernel<<<(E + 255) / 256, 256, 0, stream>>>(dst, cnt, E, B);
        alloc_kernel<<<(B + 255) / 256, 256, 0, stream>>>(cnt, off, deg, cursor, B);
        scatter_kernel<<<(E + 255) / 256, 256, 0, stream>>>(src, dst, cnt, off, bucket, E, B);
        aggregate_csr_kernel<<<(B + 3) / 4, 256, 0, stream>>>(
            (const float2*)x, off, deg, bucket, (float2*)out, B);
    }
}